// Round 4
// baseline (457.555 us; speedup 1.0000x reference)
//
#include <hip/hip_runtime.h>
#include <hip/hip_bf16.h>

// SSIM loss via MFMA band-matrix separable conv (R4 restructure).
// Out = Gv . X . Gh^T per quantity; G is the 11-tap Gaussian band matrix.
// Per 16x16 output subtile per quantity: 2 horizontal MFMAs (26 h-rows in
// 2 row-chunks, K=32 covers the 26-col band) + 1 vertical MFMA (K=32 covers
// 26 h-rows). k slots 26..31 carry exactly-zero G coefficients -> staged
// 48x48 tile needs no edge clamping (finite garbage x 0).
// Middle-result transpose: wave-PRIVATE LDS h^T buffer (m120 attention
// pattern), C-layout [row=quad*4+reg][col=lane&15] -> h^T[n][k] -> B-frag
// [k=quad*8+j][n=lane&15]. No barriers in the compute section.
// bf16 kernel sum forced to 1 via center-tap correction (systematic-bias fix).

typedef __attribute__((ext_vector_type(8))) short sh8;
typedef __attribute__((ext_vector_type(4))) float f32x4;

#define SROW 56   // staged row stride (bf16 elems): mult of 8 (b128-aligned),
                  // 28 words -> rows hit distinct banks (28m % 32 all distinct)
#define HROW 40   // h^T row stride: 20 words -> 16-B aligned, conflict-free

__device__ __forceinline__ unsigned short f2bf(float f) {
    union { __hip_bfloat16 b; unsigned short s; } u;
    u.b = __float2bfloat16(f);   // RNE
    return u.s;
}
__device__ __forceinline__ float bf2f(unsigned short s) {
    return __uint_as_float(((unsigned)s) << 16);
}

__global__ void ssim_init(float* ws) {
    if (threadIdx.x == 0) { ws[0] = 0.0f; ((unsigned*)ws)[1] = 0u; }
}

__global__ __launch_bounds__(256) void ssim_main(
    const float* __restrict__ xg, const float* __restrict__ yg,
    const float* __restrict__ w2d, float* __restrict__ ws,
    float* __restrict__ out, int nblocks, float invN)
{
    __shared__ __align__(16) unsigned short sxb[48 * SROW];
    __shared__ __align__(16) unsigned short syb[48 * SROW];
    __shared__ __align__(16) unsigned short hbuf[4][5][16 * HROW];
    __shared__ float gf[12];
    __shared__ float wred[4];

    const int tid = threadIdx.x;

    // --- 1D kernel = row sums of 2D window; pre-round to bf16 grid. ---
    if (tid < 11) {
        float s = 0.0f;
        #pragma unroll
        for (int j = 0; j < 11; ++j) s += w2d[tid * 11 + j];
        gf[tid] = bf2f(f2bf(s));
    }
    if (tid == 11) gf[11] = 0.0f;

    // --- Stage 48x48 input tile (zero-padded at image borders) as bf16. ---
    const int x0 = blockIdx.x * 32 - 5;
    const int y0 = blockIdx.y * 32 - 5;
    const size_t zoff = (size_t)blockIdx.z * (512 * 512);
    const float* __restrict__ xp = xg + zoff;
    const float* __restrict__ yp = yg + zoff;

    for (int it = tid; it < 48 * 12; it += 256) {
        const int r = it / 12;
        const int c4 = (it - r * 12) * 4;
        const int gr = y0 + r;
        const bool rok = (unsigned)gr < 512u;
        const int rowo = gr * 512;
        float fx[4], fy[4];
        #pragma unroll
        for (int j = 0; j < 4; ++j) {
            const int gc = x0 + c4 + j;
            const bool ok = rok && ((unsigned)gc < 512u);
            fx[j] = ok ? xp[rowo + gc] : 0.0f;
            fy[j] = ok ? yp[rowo + gc] : 0.0f;
        }
        *(ushort4*)&sxb[r * SROW + c4] =
            make_ushort4(f2bf(fx[0]), f2bf(fx[1]), f2bf(fx[2]), f2bf(fx[3]));
        *(ushort4*)&syb[r * SROW + c4] =
            make_ushort4(f2bf(fy[0]), f2bf(fy[1]), f2bf(fy[2]), f2bf(fy[3]));
    }
    __syncthreads();

    // Center-tap correction: make the bf16 tap set sum to exactly ~1.
    if (tid == 0) {
        float s = 0.0f;
        #pragma unroll
        for (int t = 0; t < 11; ++t) if (t != 5) s += gf[t];
        gf[5] = 1.0f - s;   // consumers apply f2bf; residual ~ulp/2
    }
    __syncthreads();

    // --- Per-wave 16x16 subtile ---
    const int lane = tid & 63;
    const int wv = tid >> 6;
    const int nn = lane & 15;       // A-frag m / B-frag n / C col
    const int quad = lane >> 4;
    const int r0 = (wv >> 1) * 16;
    const int c0 = (wv & 1) * 16;

    // Shared G fragment: value(lane,j) = g[k-nn], k = quad*8+j.
    // Serves as A for the vertical pass and B for the horizontal pass.
    sh8 gfrag;
    #pragma unroll
    for (int j = 0; j < 8; ++j) {
        const int idx = quad * 8 + j - nn;
        const int ci = ((unsigned)idx <= 10u) ? idx : 11;  // gf[11] == 0
        gfrag[j] = (short)f2bf(gf[ci]);
    }

    const f32x4 zero4 = {0.0f, 0.0f, 0.0f, 0.0f};

    // Horizontal pass: h(26x16) = X_rows . Gh^T, two 16-row chunks, 5 quantities.
    #pragma unroll
    for (int rc = 0; rc < 2; ++rc) {
        const int so = (r0 + rc * 16 + nn) * SROW + c0 + quad * 8;
        const sh8 x8 = *(const sh8*)&sxb[so];
        const sh8 y8 = *(const sh8*)&syb[so];
        sh8 xx8, yy8, xy8;
        #pragma unroll
        for (int j = 0; j < 8; ++j) {
            const float xf = bf2f((unsigned short)x8[j]);
            const float yf = bf2f((unsigned short)y8[j]);
            xx8[j] = (short)f2bf(xf * xf);
            yy8[j] = (short)f2bf(yf * yf);
            xy8[j] = (short)f2bf(xf * yf);
        }
        const f32x4 h0 = __builtin_amdgcn_mfma_f32_16x16x32_bf16(x8,  gfrag, zero4, 0, 0, 0);
        const f32x4 h1 = __builtin_amdgcn_mfma_f32_16x16x32_bf16(y8,  gfrag, zero4, 0, 0, 0);
        const f32x4 h2 = __builtin_amdgcn_mfma_f32_16x16x32_bf16(xx8, gfrag, zero4, 0, 0, 0);
        const f32x4 h3 = __builtin_amdgcn_mfma_f32_16x16x32_bf16(yy8, gfrag, zero4, 0, 0, 0);
        const f32x4 h4 = __builtin_amdgcn_mfma_f32_16x16x32_bf16(xy8, gfrag, zero4, 0, 0, 0);
        // C-frag: lane holds h[row = rc*16 + quad*4 + reg][col = nn].
        const int ho = nn * HROW + rc * 16 + quad * 4;
        *(ushort4*)&hbuf[wv][0][ho] = make_ushort4(f2bf(h0[0]), f2bf(h0[1]), f2bf(h0[2]), f2bf(h0[3]));
        *(ushort4*)&hbuf[wv][1][ho] = make_ushort4(f2bf(h1[0]), f2bf(h1[1]), f2bf(h1[2]), f2bf(h1[3]));
        *(ushort4*)&hbuf[wv][2][ho] = make_ushort4(f2bf(h2[0]), f2bf(h2[1]), f2bf(h2[2]), f2bf(h2[3]));
        *(ushort4*)&hbuf[wv][3][ho] = make_ushort4(f2bf(h3[0]), f2bf(h3[1]), f2bf(h3[2]), f2bf(h3[3]));
        *(ushort4*)&hbuf[wv][4][ho] = make_ushort4(f2bf(h4[0]), f2bf(h4[1]), f2bf(h4[2]), f2bf(h4[3]));
    }
    // Wave-private buffer: only need this wave's LDS ops drained, no barrier.
    __asm__ __volatile__("s_waitcnt lgkmcnt(0)" ::: "memory");

    // Vertical pass: Out = Gv . h, one MFMA per quantity (K=32 covers 26 rows).
    f32x4 acc[5];
    #pragma unroll
    for (int q = 0; q < 5; ++q) {
        const sh8 b8 = *(const sh8*)&hbuf[wv][q][nn * HROW + quad * 8];
        acc[q] = __builtin_amdgcn_mfma_f32_16x16x32_bf16(gfrag, b8, zero4, 0, 0, 0);
    }

    // SSIM epilogue: all 5 accs share the same (row,col) mapping per (lane,reg).
    float lsum = 0.0f;
    const float C1 = 1e-4f, C2 = 9e-4f;
    #pragma unroll
    for (int r = 0; r < 4; ++r) {
        const float mx = acc[0][r], my = acc[1][r];
        const float exx = acc[2][r], eyy = acc[3][r], exy = acc[4][r];
        const float mx2 = mx * mx, my2 = my * my, mxy = mx * my;
        const float vx = exx - mx2, vy = eyy - my2, vxy = exy - mxy;
        const float num = (2.0f * mxy + C1) * (2.0f * vxy + C2);
        const float den = (mx2 + my2 + C1) * (vx + vy + C2) + 1e-12f;
        lsum = fmaf(num, __builtin_amdgcn_rcpf(den), lsum);
    }

    // Wave reduce -> cross-wave -> one atomic; last block finalizes.
    #pragma unroll
    for (int off = 32; off > 0; off >>= 1)
        lsum += __shfl_down(lsum, off, 64);
    if ((tid & 63) == 0) wred[tid >> 6] = lsum;
    __syncthreads();
    if (tid == 0) {
        atomicAdd(&ws[0], wred[0] + wred[1] + wred[2] + wred[3]);
        __threadfence();
        const unsigned old = atomicAdd((unsigned*)ws + 1, 1u);
        if (old == (unsigned)(nblocks - 1)) {
            __threadfence();
            const float total = atomicAdd(&ws[0], 0.0f);
            out[0] = 1.0f - total * invN;
        }
    }
}

extern "C" void kernel_launch(void* const* d_in, const int* in_sizes, int n_in,
                              void* d_out, int out_size, void* d_ws, size_t ws_size,
                              hipStream_t stream) {
    const float* x   = (const float*)d_in[0];
    const float* y   = (const float*)d_in[1];
    const float* w2d = (const float*)d_in[2];  // (3,1,11,11); channels identical
    float* out = (float*)d_out;
    float* ws  = (float*)d_ws;

    const int H = 512, W = 512;
    const int total = in_sizes[0];              // 16*3*512*512
    const int Z = total / (H * W);              // 48

    ssim_init<<<1, 64, 0, stream>>>(ws);

    dim3 grid(W / 32, H / 32, Z);               // 16 x 16 x 48 = 12288 blocks
    const int nblocks = (W / 32) * (H / 32) * Z;
    const float invN = 1.0f / (float)total;
    ssim_main<<<grid, 256, 0, stream>>>(x, y, w2d, ws, out, nblocks, invN);
}